// Round 8
// baseline (4759.723 us; speedup 1.0000x reference)
//
#include <hip/hip_runtime.h>
#include <cstdint>
#include <cstddef>

// Bidirectional LSTM  B=32 T=1024 D=512 H=256 (torch gate order i,f,g,o), fp32 in/out.
//
// Phase 1: xp[m][n] = sum_k x16[m][k] * W16[n][k] + bias[n]  (fp16 MFMA GEMM, xp fp16)
// Phase 2: MFMA recurrence. One block per (dir,batch) chain, 512 threads (8 waves,
//   2/SIMD). Wave w owns outputs [32w,32w+32): M-tiles {g*16+2w+j}. ALL 64 A-frags
//   per wave live in the unified VGPR+AGPR file (256 regs; MFMA reads A from AGPR
//   natively on gfx950) -- zero in-loop weight traffic on LDS/L2/HBM.
//   B-frag: all 16 cols load the same h chunk (col-redundant). Activation via 4KB
//   LDS bounce, 1 barrier/step.

typedef unsigned int   uint;
typedef unsigned short ushort;

constexpr int Tn = 1024;
constexpr int Bn = 32;
constexpr int Dn = 512;
constexpr int Hn = 256;
constexpr int NC = 2048;          // 2 dirs * 4H
constexpr int KT = 512;           // K of the input projection

constexpr int AR = 64;            // ALL 64 A-frags per wave in registers

typedef _Float16 half8  __attribute__((ext_vector_type(8)));
typedef float    f32x4  __attribute__((ext_vector_type(4)));

__device__ __forceinline__ ushort f2h(float f) {
  _Float16 h = (_Float16)f;               // RNE
  return __builtin_bit_cast(ushort, h);
}
__device__ __forceinline__ float h2f(ushort s) {
  return (float)__builtin_bit_cast(_Float16, s);
}
__device__ __forceinline__ uint packh(float a, float b) {
  return (uint)f2h(a) | ((uint)f2h(b) << 16);
}
__device__ __forceinline__ f32x4 mf(uint4 a, uint4 b, f32x4 c) {
  return __builtin_amdgcn_mfma_f32_16x16x32_f16(
      __builtin_bit_cast(half8, a), __builtin_bit_cast(half8, b), c, 0, 0, 0);
}

__device__ __forceinline__ float sig_(float x) {
  x = fminf(fmaxf(x, -30.f), 30.f);
  return 1.f / (1.f + __expf(-x));
}
__device__ __forceinline__ float tanh_(float x) {
  x = fminf(fmaxf(x, -15.f), 15.f);
  float e = __expf(2.f * x);
  return (e - 1.f) / (e + 1.f);
}

// ---------------- prep kernels ----------------

__global__ void k_prep_a(const float* __restrict__ x, ushort* __restrict__ a16, long nquad) {
  long i4 = (long)blockIdx.x * blockDim.x + threadIdx.x;
  if (i4 >= nquad) return;
  const float4 v = ((const float4*)x)[i4];
  ushort4 o;
  o.x = f2h(v.x); o.y = f2h(v.y); o.z = f2h(v.z); o.w = f2h(v.w);
  ((ushort4*)a16)[i4] = o;
}

__global__ void k_prep_w(const float* __restrict__ wf, const float* __restrict__ wb,
                         const float* __restrict__ bf1, const float* __restrict__ bf2,
                         const float* __restrict__ bb1, const float* __restrict__ bb2,
                         ushort* __restrict__ w16, float* __restrict__ biasc) {
  long i4 = (long)blockIdx.x * blockDim.x + threadIdx.x;
  if (i4 >= (long)NC * (KT / 4)) return;
  int n = (int)(i4 >> 7);
  int k4 = (int)(i4 & 127);
  int dir = n >> 10, g = n & 1023;
  const float* w = dir ? wb : wf;
  const float4 v = ((const float4*)(w + (size_t)g * Dn))[k4];
  ushort4 o;
  o.x = f2h(v.x); o.y = f2h(v.y); o.z = f2h(v.z); o.w = f2h(v.w);
  ((ushort4*)w16)[i4] = o;
  if (k4 == 0) biasc[n] = dir ? (bb1[g] + bb2[g]) : (bf1[g] + bf2[g]);
}

// Whh -> MFMA A-fragment layout. WF[dir][wave][fidx][lane] (uint4 = half8).
// fidx = kt*8 + (g*2+j); tile = g*16 + 2*w + j; row = tile*16 + (lane&15);
// k = kt*32 + (lane>>4)*8 .. +7.
__global__ void k_prep_whh(const float* __restrict__ whhF, const float* __restrict__ whhB,
                           uint4* __restrict__ WF) {
  int t = blockIdx.x * blockDim.x + threadIdx.x;   // 0 .. 2*8*64*64-1
  if (t >= 2 * 8 * 64 * 64) return;
  int lane = t & 63;
  int fidx = (t >> 6) & 63;
  int w    = (t >> 12) & 7;
  int dir  = t >> 15;
  int kt = fidx >> 3, mi = fidx & 7;
  int g = mi >> 1, j = mi & 1;
  int row = (g * 16 + 2 * w + j) * 16 + (lane & 15);
  int kb  = kt * 32 + (lane >> 4) * 8;
  const float* whh = dir ? whhB : whhF;
  const float4* s = (const float4*)(whh + (size_t)row * Hn + kb);
  float4 v0 = s[0], v1 = s[1];
  WF[t] = (uint4){ packh(v0.x, v0.y), packh(v0.z, v0.w),
                   packh(v1.x, v1.y), packh(v1.z, v1.w) };
}

__global__ void k_bad(float* __restrict__ out, int n) {
  int i = blockIdx.x * blockDim.x + threadIdx.x;
  if (i < n) out[i] = 54321.f;
}

// ---------------- phase 1: fp16 MFMA GEMM ----------------

__device__ __forceinline__ void gload_lds16(const void* g, void* l) {
  __builtin_amdgcn_global_load_lds((const __attribute__((address_space(1))) void*)g,
                                   (__attribute__((address_space(3))) void*)l, 16, 0, 0);
}

__global__ __launch_bounds__(256) void k_gemm(const ushort* __restrict__ A,
                                              const ushort* __restrict__ W,
                                              const float* __restrict__ biasc,
                                              ushort* __restrict__ xp) {
  __shared__ __align__(16) ushort As[128 * 32];
  __shared__ __align__(16) ushort Bs[128 * 32];
  const int bid = blockIdx.x;
  const int m0 = (bid >> 4) * 128;
  const int n0 = (bid & 15) * 128;
  const int tid = threadIdx.x;
  const int wid = tid >> 6, lane = tid & 63;
  const int wr = wid >> 1, wcq = wid & 1;
  const int l16 = lane & 15, lq = lane >> 4;

  f32x4 acc[4][4] = {};

  for (int kt = 0; kt < KT; kt += 32) {
    __syncthreads();
#pragma unroll
    for (int i = 0; i < 2; ++i) {
      int ch = wid * 2 + i;
      int p = ch * 64 + lane;
      int r = p >> 2, gp = p & 3;
      int gs = gp ^ ((r >> 1) & 3);
      gload_lds16(A + (size_t)(m0 + r) * KT + kt + gs * 8, (char*)As + ch * 1024);
      gload_lds16(W + (size_t)(n0 + r) * KT + kt + gs * 8, (char*)Bs + ch * 1024);
    }
    __syncthreads();

    half8 af[4], bfr[4];
#pragma unroll
    for (int mfi = 0; mfi < 4; ++mfi) {
      int row = wr * 64 + mfi * 16 + l16;
      int g = lq ^ ((row >> 1) & 3);
      af[mfi] = *(const half8*)((const char*)As + row * 64 + g * 16);
    }
#pragma unroll
    for (int nf = 0; nf < 4; ++nf) {
      int row = wcq * 64 + nf * 16 + l16;
      int g = lq ^ ((row >> 1) & 3);
      bfr[nf] = *(const half8*)((const char*)Bs + row * 64 + g * 16);
    }
#pragma unroll
    for (int mfi = 0; mfi < 4; ++mfi)
#pragma unroll
      for (int nf = 0; nf < 4; ++nf)
        acc[mfi][nf] = __builtin_amdgcn_mfma_f32_16x16x32_f16(af[mfi], bfr[nf], acc[mfi][nf], 0, 0, 0);
  }

#pragma unroll
  for (int nf = 0; nf < 4; ++nf) {
    int col = n0 + wcq * 64 + nf * 16 + l16;
    float bv = biasc[col];
#pragma unroll
    for (int mfi = 0; mfi < 4; ++mfi) {
      int rbase = m0 + wr * 64 + mfi * 16 + lq * 4;
#pragma unroll
      for (int i = 0; i < 4; ++i)
        xp[(size_t)(rbase + i) * NC + col] = f2h(acc[mfi][nf][i] + bv);
    }
  }
}

// ---------------- phase 2: MFMA recurrence, all weights in registers ----------------

__global__ __launch_bounds__(512, 2) void k_lstm(const uint4* __restrict__ WF,
                                                 const ushort* __restrict__ xp,
                                                 float* __restrict__ out,
                                                 int b_base) {
  const int dir = blockIdx.x & 1;
  const int bl  = blockIdx.x >> 1;
  const int tid = threadIdx.x;
  const int w    = tid >> 6;
  const int lane = tid & 63;
  const int lq   = lane >> 4;      // k-chunk / row-quad
  const int n    = lane & 31;      // this lane's output within the wave (2x redundant)

  __shared__ float  gbuf[8][128];                   // 4 KB gate bounce
  __shared__ ushort hp[2][256];                     // 1 KB h double buffer

  // ---- persistent weights: all 64 frags in unified VGPR+AGPR file ----
  const uint4* wfb = WF + (size_t)((dir * 8 + w) * 64) * 64 + lane;
  uint4 wA[AR];
#pragma unroll
  for (int f = 0; f < AR; ++f) wA[f] = wfb[(size_t)f * 64];

  if (tid < 256) { hp[0][tid] = 0; hp[1][tid] = 0; }
  float creg = 0.f;
  __syncthreads();

  const int dstep = dir ? -1 : 1;
  const ptrdiff_t xstr = (ptrdiff_t)dstep * NC;
  const ptrdiff_t ostr = (ptrdiff_t)dstep * 512;
  const int t0 = dir ? (Tn - 1) : 0;
  const ushort* px = xp + (size_t)(bl * Tn + t0) * NC + dir * 1024 + 32 * w + n;
  float* pout = out + (size_t)((b_base + bl) * Tn + t0) * 512 + dir * 256 + 32 * w + n;

#pragma unroll 1
  for (int t = 0; t < Tn; ++t) {
    const int cur = t & 1;
    // xp for this lane's output (consumed at step end; latency hidden under MFMA)
    ushort xg0 = px[0], xg1 = px[256], xg2 = px[512], xg3 = px[768];
    if (t + 1 < Tn) px += xstr;

    f32x4 acc[4][2];
#pragma unroll
    for (int g = 0; g < 4; ++g)
#pragma unroll
      for (int j = 0; j < 2; ++j) acc[g][j] = (f32x4){0.f, 0.f, 0.f, 0.f};

    // B phase 1: kt 0..3 (every lane loads the same h chunk -> all cols equal)
    uint4 b[4];
#pragma unroll
    for (int kt = 0; kt < 4; ++kt)
      b[kt] = *(const uint4*)((const char*)hp + cur * 512 + kt * 64 + lq * 16);

#pragma unroll
    for (int kt = 0; kt < 4; ++kt)
#pragma unroll
      for (int m = 0; m < 8; ++m)
        acc[m >> 1][m & 1] = mf(wA[kt * 8 + m], b[kt], acc[m >> 1][m & 1]);

    // B phase 2: kt 4..7
#pragma unroll
    for (int kt = 0; kt < 4; ++kt)
      b[kt] = *(const uint4*)((const char*)hp + cur * 512 + (kt + 4) * 64 + lq * 16);

#pragma unroll
    for (int kt = 0; kt < 4; ++kt)
#pragma unroll
      for (int m = 0; m < 8; ++m)
        acc[m >> 1][m & 1] = mf(wA[(kt + 4) * 8 + m], b[kt], acc[m >> 1][m & 1]);

    // ---- gate bounce: col-0 lane groups write D rows, every lane reads its output ----
    if ((lane & 15) == 0) {
#pragma unroll
      for (int g = 0; g < 4; ++g)
#pragma unroll
        for (int j = 0; j < 2; ++j)
          *(f32x4*)&gbuf[w][g * 32 + j * 16 + lq * 4] = acc[g][j];
    }
    // same-wave LDS dependency: compiler inserts lgkmcnt
    float gi = gbuf[w][0 * 32 + n] + h2f(xg0);
    float gf = gbuf[w][1 * 32 + n] + h2f(xg1);
    float gg = gbuf[w][2 * 32 + n] + h2f(xg2);
    float go = gbuf[w][3 * 32 + n] + h2f(xg3);
    float iv = sig_(gi), fv = sig_(gf), gv = tanh_(gg), ov = sig_(go);
    creg = fv * creg + iv * gv;
    float h = ov * tanh_(creg);
    if (lane < 32) {
      *pout = h;
      hp[cur ^ 1][32 * w + n] = f2h(h);
    }
    pout += ostr;
    __syncthreads();
  }
}

// ---------------- host ----------------

extern "C" void kernel_launch(void* const* d_in, const int* in_sizes, int n_in,
                              void* d_out, int out_size, void* d_ws, size_t ws_size,
                              hipStream_t stream) {
  const float* x     = (const float*)d_in[0];
  const float* Wih_f = (const float*)d_in[1];
  const float* Whh_f = (const float*)d_in[2];
  const float* bih_f = (const float*)d_in[3];
  const float* bhh_f = (const float*)d_in[4];
  const float* Wih_b = (const float*)d_in[5];
  const float* Whh_b = (const float*)d_in[6];
  const float* bib_b = (const float*)d_in[7];
  const float* bhh_b = (const float*)d_in[8];
  float* out = (float*)d_out;

  const size_t szW16  = (size_t)NC * KT * 2;            // 2 MiB
  const size_t szBias = (size_t)NC * 4;
  const size_t szWF   = (size_t)2 * 8 * 64 * 64 * 16;   // 1 MiB frag buffer

  int c = 0;
  size_t szA16 = 0, szXp = 0;
  for (int cc = 1; cc <= 16; cc *= 2) {
    size_t a = (size_t)(Bn / cc) * Tn * KT * 2;
    size_t p = (size_t)(Bn / cc) * Tn * NC * 2;
    if (szW16 + szBias + szWF + a + p <= ws_size) { c = cc; szA16 = a; szXp = p; break; }
  }
  if (c == 0) {
    k_bad<<<(out_size + 255) / 256, 256, 0, stream>>>(out, out_size);
    return;
  }

  char* ws = (char*)d_ws;
  ushort* W16   = (ushort*)ws;
  float*  biasc = (float*)(ws + szW16);
  uint4*  WF    = (uint4*)(ws + szW16 + szBias);
  ushort* A16   = (ushort*)(ws + szW16 + szBias + szWF);
  ushort* xp    = (ushort*)(ws + szW16 + szBias + szWF + szA16);

  {
    long n4 = (long)NC * (KT / 4);
    k_prep_w<<<(int)((n4 + 255) / 256), 256, 0, stream>>>(Wih_f, Wih_b, bih_f, bhh_f,
                                                          bib_b, bhh_b, W16, biasc);
  }
  k_prep_whh<<<(2 * 8 * 64 * 64) / 256, 256, 0, stream>>>(Whh_f, Whh_b, WF);

  const int sizeB = Bn / c;
  for (int cb = 0; cb < c; ++cb) {
    const int b_base = cb * sizeB;
    {
      long nquad = (long)sizeB * Tn * KT / 4;
      k_prep_a<<<(int)((nquad + 255) / 256), 256, 0, stream>>>(
          x + (size_t)b_base * Tn * Dn, A16, nquad);
    }
    k_gemm<<<dim3(sizeB * 8 * 16), dim3(256), 0, stream>>>(A16, W16, biasc, xp);
    k_lstm<<<dim3(2 * sizeB), dim3(512), 0, stream>>>(WF, xp, out, b_base);
  }
}

// Round 9
// 1834.390 us; speedup vs baseline: 2.5947x; 2.5947x over previous
//
#include <hip/hip_runtime.h>
#include <cstdint>
#include <cstddef>

// Bidirectional LSTM  B=32 T=1024 D=512 H=256 (torch gate order i,f,g,o), fp32 in/out.
//
// Phase 1: xp[m][n] = sum_k x16[m][k] * W16[n][k] + bias[n]  (fp16 MFMA GEMM, xp fp16)
// Phase 2: MFMA recurrence. One block per (dir,batch) chain, 512 threads (8 waves,
//   2/SIMD -> 256-reg unified budget/wave). Wave w owns outputs [32w,32w+32):
//   M-tiles {g*16+2w+j}. 45 A-frags in regs + 19 in LDS (register file = 512KB/CU =
//   exactly Whh size; ~20% must overflow to LDS). m-major tile loop: per tile,
//   LDS-frag reads at top, 2 acc chains (p,q), inline gbuf bounce-write -> tail
//   overlap. 1 barrier/step.

typedef unsigned int   uint;
typedef unsigned short ushort;

constexpr int Tn = 1024;
constexpr int Bn = 32;
constexpr int Dn = 512;
constexpr int Hn = 256;
constexpr int NC = 2048;          // 2 dirs * 4H
constexpr int KT = 512;           // K of the input projection

constexpr int ALN = 19;           // LDS-resident A frags per wave

typedef _Float16 half8  __attribute__((ext_vector_type(8)));
typedef float    f32x4  __attribute__((ext_vector_type(4)));

__device__ __forceinline__ ushort f2h(float f) {
  _Float16 h = (_Float16)f;               // RNE
  return __builtin_bit_cast(ushort, h);
}
__device__ __forceinline__ float h2f(ushort s) {
  return (float)__builtin_bit_cast(_Float16, s);
}
__device__ __forceinline__ uint packh(float a, float b) {
  return (uint)f2h(a) | ((uint)f2h(b) << 16);
}
__device__ __forceinline__ f32x4 mf(uint4 a, uint4 b, f32x4 c) {
  return __builtin_amdgcn_mfma_f32_16x16x32_f16(
      __builtin_bit_cast(half8, a), __builtin_bit_cast(half8, b), c, 0, 0, 0);
}

__device__ __forceinline__ float sig_(float x) {
  x = fminf(fmaxf(x, -30.f), 30.f);
  return 1.f / (1.f + __expf(-x));
}
__device__ __forceinline__ float tanh_(float x) {
  x = fminf(fmaxf(x, -15.f), 15.f);
  float e = __expf(2.f * x);
  return (e - 1.f) / (e + 1.f);
}

// ---------------- prep kernels ----------------

__global__ void k_prep_a(const float* __restrict__ x, ushort* __restrict__ a16, long nquad) {
  long i4 = (long)blockIdx.x * blockDim.x + threadIdx.x;
  if (i4 >= nquad) return;
  const float4 v = ((const float4*)x)[i4];
  ushort4 o;
  o.x = f2h(v.x); o.y = f2h(v.y); o.z = f2h(v.z); o.w = f2h(v.w);
  ((ushort4*)a16)[i4] = o;
}

__global__ void k_prep_w(const float* __restrict__ wf, const float* __restrict__ wb,
                         const float* __restrict__ bf1, const float* __restrict__ bf2,
                         const float* __restrict__ bb1, const float* __restrict__ bb2,
                         ushort* __restrict__ w16, float* __restrict__ biasc) {
  long i4 = (long)blockIdx.x * blockDim.x + threadIdx.x;
  if (i4 >= (long)NC * (KT / 4)) return;
  int n = (int)(i4 >> 7);
  int k4 = (int)(i4 & 127);
  int dir = n >> 10, g = n & 1023;
  const float* w = dir ? wb : wf;
  const float4 v = ((const float4*)(w + (size_t)g * Dn))[k4];
  ushort4 o;
  o.x = f2h(v.x); o.y = f2h(v.y); o.z = f2h(v.z); o.w = f2h(v.w);
  ((ushort4*)w16)[i4] = o;
  if (k4 == 0) biasc[n] = dir ? (bb1[g] + bb2[g]) : (bf1[g] + bf2[g]);
}

// Whh -> MFMA A-fragment layout. WF[dir][wave][fidx][lane] (uint4 = half8).
// fidx = kt*8 + (g*2+j); tile = g*16 + 2*w + j; row = tile*16 + (lane&15);
// k = kt*32 + (lane>>4)*8 .. +7.
__global__ void k_prep_whh(const float* __restrict__ whhF, const float* __restrict__ whhB,
                           uint4* __restrict__ WF) {
  int t = blockIdx.x * blockDim.x + threadIdx.x;   // 0 .. 2*8*64*64-1
  if (t >= 2 * 8 * 64 * 64) return;
  int lane = t & 63;
  int fidx = (t >> 6) & 63;
  int w    = (t >> 12) & 7;
  int dir  = t >> 15;
  int kt = fidx >> 3, mi = fidx & 7;
  int g = mi >> 1, j = mi & 1;
  int row = (g * 16 + 2 * w + j) * 16 + (lane & 15);
  int kb  = kt * 32 + (lane >> 4) * 8;
  const float* whh = dir ? whhB : whhF;
  const float4* s = (const float4*)(whh + (size_t)row * Hn + kb);
  float4 v0 = s[0], v1 = s[1];
  WF[t] = (uint4){ packh(v0.x, v0.y), packh(v0.z, v0.w),
                   packh(v1.x, v1.y), packh(v1.z, v1.w) };
}

__global__ void k_bad(float* __restrict__ out, int n) {
  int i = blockIdx.x * blockDim.x + threadIdx.x;
  if (i < n) out[i] = 54321.f;
}

// ---------------- phase 1: fp16 MFMA GEMM ----------------

__device__ __forceinline__ void gload_lds16(const void* g, void* l) {
  __builtin_amdgcn_global_load_lds((const __attribute__((address_space(1))) void*)g,
                                   (__attribute__((address_space(3))) void*)l, 16, 0, 0);
}

__global__ __launch_bounds__(256) void k_gemm(const ushort* __restrict__ A,
                                              const ushort* __restrict__ W,
                                              const float* __restrict__ biasc,
                                              ushort* __restrict__ xp) {
  __shared__ __align__(16) ushort As[128 * 32];
  __shared__ __align__(16) ushort Bs[128 * 32];
  const int bid = blockIdx.x;
  const int m0 = (bid >> 4) * 128;
  const int n0 = (bid & 15) * 128;
  const int tid = threadIdx.x;
  const int wid = tid >> 6, lane = tid & 63;
  const int wr = wid >> 1, wcq = wid & 1;
  const int l16 = lane & 15, lq = lane >> 4;

  f32x4 acc[4][4] = {};

  for (int kt = 0; kt < KT; kt += 32) {
    __syncthreads();
#pragma unroll
    for (int i = 0; i < 2; ++i) {
      int ch = wid * 2 + i;
      int p = ch * 64 + lane;
      int r = p >> 2, gp = p & 3;
      int gs = gp ^ ((r >> 1) & 3);
      gload_lds16(A + (size_t)(m0 + r) * KT + kt + gs * 8, (char*)As + ch * 1024);
      gload_lds16(W + (size_t)(n0 + r) * KT + kt + gs * 8, (char*)Bs + ch * 1024);
    }
    __syncthreads();

    half8 af[4], bfr[4];
#pragma unroll
    for (int mfi = 0; mfi < 4; ++mfi) {
      int row = wr * 64 + mfi * 16 + l16;
      int g = lq ^ ((row >> 1) & 3);
      af[mfi] = *(const half8*)((const char*)As + row * 64 + g * 16);
    }
#pragma unroll
    for (int nf = 0; nf < 4; ++nf) {
      int row = wcq * 64 + nf * 16 + l16;
      int g = lq ^ ((row >> 1) & 3);
      bfr[nf] = *(const half8*)((const char*)Bs + row * 64 + g * 16);
    }
#pragma unroll
    for (int mfi = 0; mfi < 4; ++mfi)
#pragma unroll
      for (int nf = 0; nf < 4; ++nf)
        acc[mfi][nf] = __builtin_amdgcn_mfma_f32_16x16x32_f16(af[mfi], bfr[nf], acc[mfi][nf], 0, 0, 0);
  }

#pragma unroll
  for (int nf = 0; nf < 4; ++nf) {
    int col = n0 + wcq * 64 + nf * 16 + l16;
    float bv = biasc[col];
#pragma unroll
    for (int mfi = 0; mfi < 4; ++mfi) {
      int rbase = m0 + wr * 64 + mfi * 16 + lq * 4;
#pragma unroll
      for (int i = 0; i < 4; ++i)
        xp[(size_t)(rbase + i) * NC + col] = f2h(acc[mfi][nf][i] + bv);
    }
  }
}

// ---------------- phase 2: MFMA recurrence, m-major with inline bounce ----------------
// Reg/LDS split per tile: tiles 0..4: kt0-5 reg (wA6), kt6-7 LDS (slots 2m,2m+1);
// tiles 5..7: kt0-4 reg (wA5), kt5-7 LDS (slots 10+3(m-5)+kt-5). 45 reg + 19 LDS frags.

__global__ __launch_bounds__(512, 2) void k_lstm(const uint4* __restrict__ WF,
                                                 const ushort* __restrict__ xp,
                                                 float* __restrict__ out,
                                                 int b_base) {
  const int dir = blockIdx.x & 1;
  const int bl  = blockIdx.x >> 1;
  const int tid = threadIdx.x;
  const int w    = tid >> 6;
  const int lane = tid & 63;
  const int lq   = lane >> 4;      // k-chunk / row-quad
  const int n    = lane & 31;      // this lane's output within the wave (2x redundant)

  __shared__ __align__(16) uint4  AL[8][ALN][64];   // 152 KB LDS A-frags
  __shared__ float  gbuf[8][128];                   // 4 KB gate bounce
  __shared__ ushort hp[2][256];                     // 1 KB h double buffer

  // ---- persistent weights ----
  const uint4* wfb = WF + (size_t)((dir * 8 + w) * 64) * 64 + lane;
  uint4 wA6[5][6];                 // tiles 0..4, kt 0..5  (30 frags)
  uint4 wA5[3][5];                 // tiles 5..7, kt 0..4  (15 frags)
#pragma unroll
  for (int m = 0; m < 5; ++m)
#pragma unroll
    for (int kt = 0; kt < 6; ++kt)
      wA6[m][kt] = wfb[(size_t)(kt * 8 + m) * 64];
#pragma unroll
  for (int m = 5; m < 8; ++m)
#pragma unroll
    for (int kt = 0; kt < 5; ++kt)
      wA5[m - 5][kt] = wfb[(size_t)(kt * 8 + m) * 64];
#pragma unroll
  for (int m = 0; m < 5; ++m) {
    AL[w][2 * m + 0][lane] = wfb[(size_t)(6 * 8 + m) * 64];
    AL[w][2 * m + 1][lane] = wfb[(size_t)(7 * 8 + m) * 64];
  }
#pragma unroll
  for (int m = 5; m < 8; ++m)
#pragma unroll
    for (int kt = 5; kt < 8; ++kt)
      AL[w][10 + 3 * (m - 5) + (kt - 5)][lane] = wfb[(size_t)(kt * 8 + m) * 64];

  if (tid < 256) { hp[0][tid] = 0; hp[1][tid] = 0; }
  float creg = 0.f;
  __syncthreads();

  const int dstep = dir ? -1 : 1;
  const ptrdiff_t xstr = (ptrdiff_t)dstep * NC;
  const ptrdiff_t ostr = (ptrdiff_t)dstep * 512;
  const int t0 = dir ? (Tn - 1) : 0;
  const ushort* px = xp + (size_t)(bl * Tn + t0) * NC + dir * 1024 + 32 * w + n;
  float* pout = out + (size_t)((b_base + bl) * Tn + t0) * 512 + dir * 256 + 32 * w + n;

#pragma unroll 1
  for (int t = 0; t < Tn; ++t) {
    const int cur = t & 1;
    // xp for this lane's output (consumed at step end; latency hidden under MFMA)
    ushort xg0 = px[0], xg1 = px[256], xg2 = px[512], xg3 = px[768];
    if (t + 1 < Tn) px += xstr;

    // all 8 B chunks (uniform 16B broadcast reads)
    uint4 b[8];
#pragma unroll
    for (int kt = 0; kt < 8; ++kt)
      b[kt] = *(const uint4*)((const char*)hp + cur * 512 + kt * 64 + lq * 16);

    // tiles 0..4: LDS reads at top, 2 acc chains, inline bounce
#pragma unroll
    for (int m = 0; m < 5; ++m) {
      uint4 l0 = AL[w][2 * m + 0][lane];
      uint4 l1 = AL[w][2 * m + 1][lane];
      f32x4 p = {0.f, 0.f, 0.f, 0.f}, q = {0.f, 0.f, 0.f, 0.f};
      p = mf(wA6[m][0], b[0], p);
      q = mf(wA6[m][1], b[1], q);
      p = mf(wA6[m][2], b[2], p);
      q = mf(wA6[m][3], b[3], q);
      p = mf(wA6[m][4], b[4], p);
      q = mf(wA6[m][5], b[5], q);
      p = mf(l0, b[6], p);
      q = mf(l1, b[7], q);
      if ((lane & 15) == 0) {
        const int g = m >> 1, j = m & 1;
        *(f32x4*)&gbuf[w][g * 32 + j * 16 + lq * 4] = p + q;
      }
    }
    // tiles 5..7
#pragma unroll
    for (int mm = 0; mm < 3; ++mm) {
      const int m = 5 + mm;
      uint4 l0 = AL[w][10 + 3 * mm + 0][lane];
      uint4 l1 = AL[w][10 + 3 * mm + 1][lane];
      uint4 l2 = AL[w][10 + 3 * mm + 2][lane];
      f32x4 p = {0.f, 0.f, 0.f, 0.f}, q = {0.f, 0.f, 0.f, 0.f};
      p = mf(wA5[mm][0], b[0], p);
      q = mf(wA5[mm][1], b[1], q);
      p = mf(wA5[mm][2], b[2], p);
      q = mf(wA5[mm][3], b[3], q);
      p = mf(wA5[mm][4], b[4], p);
      q = mf(l0, b[5], q);
      p = mf(l1, b[6], p);
      q = mf(l2, b[7], q);
      if ((lane & 15) == 0) {
        const int g = m >> 1, j = m & 1;
        *(f32x4*)&gbuf[w][g * 32 + j * 16 + lq * 4] = p + q;
      }
    }

    // ---- tail: read own gates, activate, write h ----
    float gi = gbuf[w][0 * 32 + n] + h2f(xg0);
    float gf = gbuf[w][1 * 32 + n] + h2f(xg1);
    float gg = gbuf[w][2 * 32 + n] + h2f(xg2);
    float go = gbuf[w][3 * 32 + n] + h2f(xg3);
    float iv = sig_(gi), fv = sig_(gf), gv = tanh_(gg), ov = sig_(go);
    creg = fv * creg + iv * gv;
    float h = ov * tanh_(creg);
    if (lane < 32) {
      *pout = h;
      hp[cur ^ 1][32 * w + n] = f2h(h);
    }
    pout += ostr;
    __syncthreads();
  }
}

// ---------------- host ----------------

extern "C" void kernel_launch(void* const* d_in, const int* in_sizes, int n_in,
                              void* d_out, int out_size, void* d_ws, size_t ws_size,
                              hipStream_t stream) {
  const float* x     = (const float*)d_in[0];
  const float* Wih_f = (const float*)d_in[1];
  const float* Whh_f = (const float*)d_in[2];
  const float* bih_f = (const float*)d_in[3];
  const float* bhh_f = (const float*)d_in[4];
  const float* Wih_b = (const float*)d_in[5];
  const float* Whh_b = (const float*)d_in[6];
  const float* bib_b = (const float*)d_in[7];
  const float* bhh_b = (const float*)d_in[8];
  float* out = (float*)d_out;

  const size_t szW16  = (size_t)NC * KT * 2;            // 2 MiB
  const size_t szBias = (size_t)NC * 4;
  const size_t szWF   = (size_t)2 * 8 * 64 * 64 * 16;   // 1 MiB frag buffer

  int c = 0;
  size_t szA16 = 0, szXp = 0;
  for (int cc = 1; cc <= 16; cc *= 2) {
    size_t a = (size_t)(Bn / cc) * Tn * KT * 2;
    size_t p = (size_t)(Bn / cc) * Tn * NC * 2;
    if (szW16 + szBias + szWF + a + p <= ws_size) { c = cc; szA16 = a; szXp = p; break; }
  }
  if (c == 0) {
    k_bad<<<(out_size + 255) / 256, 256, 0, stream>>>(out, out_size);
    return;
  }

  char* ws = (char*)d_ws;
  ushort* W16   = (ushort*)ws;
  float*  biasc = (float*)(ws + szW16);
  uint4*  WF    = (uint4*)(ws + szW16 + szBias);
  ushort* A16   = (ushort*)(ws + szW16 + szBias + szWF);
  ushort* xp    = (ushort*)(ws + szW16 + szBias + szWF + szA16);

  {
    long n4 = (long)NC * (KT / 4);
    k_prep_w<<<(int)((n4 + 255) / 256), 256, 0, stream>>>(Wih_f, Wih_b, bih_f, bhh_f,
                                                          bib_b, bhh_b, W16, biasc);
  }
  k_prep_whh<<<(2 * 8 * 64 * 64) / 256, 256, 0, stream>>>(Whh_f, Whh_b, WF);

  const int sizeB = Bn / c;
  for (int cb = 0; cb < c; ++cb) {
    const int b_base = cb * sizeB;
    {
      long nquad = (long)sizeB * Tn * KT / 4;
      k_prep_a<<<(int)((nquad + 255) / 256), 256, 0, stream>>>(
          x + (size_t)b_base * Tn * Dn, A16, nquad);
    }
    k_gemm<<<dim3(sizeB * 8 * 16), dim3(256), 0, stream>>>(A16, W16, biasc, xp);
    k_lstm<<<dim3(2 * sizeB), dim3(512), 0, stream>>>(WF, xp, out, b_base);
  }
}

// Round 10
// 1660.459 us; speedup vs baseline: 2.8665x; 1.1047x over previous
//
#include <hip/hip_runtime.h>
#include <cstdint>
#include <cstddef>

// Bidirectional LSTM  B=32 T=1024 D=512 H=256 (torch gate order i,f,g,o), fp32 in/out.
//
// Phase 1: xp = x @ Wih^T + bias  (fp16 MFMA GEMM, xp fp16)  [unchanged from R9]
// Phase 2: MFMA recurrence, 2-way M-split. Block = (dir, batch, half); owns 512 gate
//   rows = 128 outputs; 8 waves; wave w owns outputs w*16..w*16+15 (M-tiles = 4 gates).
//   All 32 A-frags/wave in REGISTERS (128 regs) -- no LDS/L2 weight traffic.
//   Cross-block h exchange: 8B atomic {h fp32, version} per output, parity
//   double-buffered (EX[2]); step t polls version t (posted at peer's step t-1 tail,
//   ~1 step old -> zero expected wait, hidden under phase-1 local-kt MFMAs).
//   Barriers are lgkmcnt-only + s_barrier (no vmcnt drain of out/EX stores).

typedef unsigned int   uint;
typedef unsigned short ushort;
typedef unsigned long long ull;

constexpr int Tn = 1024;
constexpr int Bn = 32;
constexpr int Dn = 512;
constexpr int Hn = 256;
constexpr int NC = 2048;          // 2 dirs * 4H
constexpr int KT = 512;           // K of the input projection
constexpr int NBmax = 128;        // max recurrence blocks (EX stride)

typedef _Float16 half8  __attribute__((ext_vector_type(8)));
typedef float    f32x4  __attribute__((ext_vector_type(4)));

__device__ __forceinline__ ushort f2h(float f) {
  _Float16 h = (_Float16)f;               // RNE
  return __builtin_bit_cast(ushort, h);
}
__device__ __forceinline__ float h2f(ushort s) {
  return (float)__builtin_bit_cast(_Float16, s);
}
__device__ __forceinline__ uint packh(float a, float b) {
  return (uint)f2h(a) | ((uint)f2h(b) << 16);
}
__device__ __forceinline__ f32x4 mf(uint4 a, uint4 b, f32x4 c) {
  return __builtin_amdgcn_mfma_f32_16x16x32_f16(
      __builtin_bit_cast(half8, a), __builtin_bit_cast(half8, b), c, 0, 0, 0);
}

__device__ __forceinline__ float sig_(float x) {
  x = fminf(fmaxf(x, -30.f), 30.f);
  return 1.f / (1.f + __expf(-x));
}
__device__ __forceinline__ float tanh_(float x) {
  x = fminf(fmaxf(x, -15.f), 15.f);
  float e = __expf(2.f * x);
  return (e - 1.f) / (e + 1.f);
}

// lgkm-only block barrier (no vmcnt drain: out/EX stores stay in flight)
__device__ __forceinline__ void barrier_lgkm() {
  asm volatile("s_waitcnt lgkmcnt(0)" ::: "memory");
  __builtin_amdgcn_s_barrier();
}

// ---------------- prep kernels ----------------

__global__ void k_prep_a(const float* __restrict__ x, ushort* __restrict__ a16, long nquad) {
  long i4 = (long)blockIdx.x * blockDim.x + threadIdx.x;
  if (i4 >= nquad) return;
  const float4 v = ((const float4*)x)[i4];
  ushort4 o;
  o.x = f2h(v.x); o.y = f2h(v.y); o.z = f2h(v.z); o.w = f2h(v.w);
  ((ushort4*)a16)[i4] = o;
}

__global__ void k_prep_w(const float* __restrict__ wf, const float* __restrict__ wb,
                         const float* __restrict__ bf1, const float* __restrict__ bf2,
                         const float* __restrict__ bb1, const float* __restrict__ bb2,
                         ushort* __restrict__ w16, float* __restrict__ biasc) {
  long i4 = (long)blockIdx.x * blockDim.x + threadIdx.x;
  if (i4 >= (long)NC * (KT / 4)) return;
  int n = (int)(i4 >> 7);
  int k4 = (int)(i4 & 127);
  int dir = n >> 10, g = n & 1023;
  const float* w = dir ? wb : wf;
  const float4 v = ((const float4*)(w + (size_t)g * Dn))[k4];
  ushort4 o;
  o.x = f2h(v.x); o.y = f2h(v.y); o.z = f2h(v.z); o.w = f2h(v.w);
  ((ushort4*)w16)[i4] = o;
  if (k4 == 0) biasc[n] = dir ? (bb1[g] + bb2[g]) : (bf1[g] + bf2[g]);
}

// Whh -> A-frags in per-(dir,half,wave) consumption order.
// frag = ((dir*2+half)*8 + w)*32 + p*4 + g ; phase p=0..7 (local kts first):
// ktphys = (p + 4*half) & 7 ; row = g*256 + half*128 + w*16 + (lane&15);
// k = ktphys*32 + (lane>>4)*8.
__global__ void k_prep_whh(const float* __restrict__ whhF, const float* __restrict__ whhB,
                           uint4* __restrict__ WF) {
  int t = blockIdx.x * blockDim.x + threadIdx.x;   // 0 .. 1024*64-1
  if (t >= 1024 * 64) return;
  int lane = t & 63;
  int frag = t >> 6;
  int g    = frag & 3;
  int p    = (frag >> 2) & 7;
  int w    = (frag >> 5) & 7;
  int half = (frag >> 8) & 1;
  int dir  = (frag >> 9) & 1;
  int row = g * 256 + half * 128 + w * 16 + (lane & 15);
  int ktphys = (p + 4 * half) & 7;
  int kb = ktphys * 32 + (lane >> 4) * 8;
  const float* whh = dir ? whhB : whhF;
  const float4* s = (const float4*)(whh + (size_t)row * Hn + kb);
  float4 v0 = s[0], v1 = s[1];
  WF[t] = (uint4){ packh(v0.x, v0.y), packh(v0.z, v0.w),
                   packh(v1.x, v1.y), packh(v1.z, v1.w) };
}

__global__ void k_bad(float* __restrict__ out, int n) {
  int i = blockIdx.x * blockDim.x + threadIdx.x;
  if (i < n) out[i] = 54321.f;
}

// ---------------- phase 1: fp16 MFMA GEMM (unchanged) ----------------

__device__ __forceinline__ void gload_lds16(const void* g, void* l) {
  __builtin_amdgcn_global_load_lds((const __attribute__((address_space(1))) void*)g,
                                   (__attribute__((address_space(3))) void*)l, 16, 0, 0);
}

__global__ __launch_bounds__(256) void k_gemm(const ushort* __restrict__ A,
                                              const ushort* __restrict__ W,
                                              const float* __restrict__ biasc,
                                              ushort* __restrict__ xp) {
  __shared__ __align__(16) ushort As[128 * 32];
  __shared__ __align__(16) ushort Bs[128 * 32];
  const int bid = blockIdx.x;
  const int m0 = (bid >> 4) * 128;
  const int n0 = (bid & 15) * 128;
  const int tid = threadIdx.x;
  const int wid = tid >> 6, lane = tid & 63;
  const int wr = wid >> 1, wcq = wid & 1;
  const int l16 = lane & 15, lq = lane >> 4;

  f32x4 acc[4][4] = {};

  for (int kt = 0; kt < KT; kt += 32) {
    __syncthreads();
#pragma unroll
    for (int i = 0; i < 2; ++i) {
      int ch = wid * 2 + i;
      int p = ch * 64 + lane;
      int r = p >> 2, gp = p & 3;
      int gs = gp ^ ((r >> 1) & 3);
      gload_lds16(A + (size_t)(m0 + r) * KT + kt + gs * 8, (char*)As + ch * 1024);
      gload_lds16(W + (size_t)(n0 + r) * KT + kt + gs * 8, (char*)Bs + ch * 1024);
    }
    __syncthreads();

    half8 af[4], bfr[4];
#pragma unroll
    for (int mfi = 0; mfi < 4; ++mfi) {
      int row = wr * 64 + mfi * 16 + l16;
      int g = lq ^ ((row >> 1) & 3);
      af[mfi] = *(const half8*)((const char*)As + row * 64 + g * 16);
    }
#pragma unroll
    for (int nf = 0; nf < 4; ++nf) {
      int row = wcq * 64 + nf * 16 + l16;
      int g = lq ^ ((row >> 1) & 3);
      bfr[nf] = *(const half8*)((const char*)Bs + row * 64 + g * 16);
    }
#pragma unroll
    for (int mfi = 0; mfi < 4; ++mfi)
#pragma unroll
      for (int nf = 0; nf < 4; ++nf)
        acc[mfi][nf] = __builtin_amdgcn_mfma_f32_16x16x32_f16(af[mfi], bfr[nf], acc[mfi][nf], 0, 0, 0);
  }

#pragma unroll
  for (int nf = 0; nf < 4; ++nf) {
    int col = n0 + wcq * 64 + nf * 16 + l16;
    float bv = biasc[col];
#pragma unroll
    for (int mfi = 0; mfi < 4; ++mfi) {
      int rbase = m0 + wr * 64 + mfi * 16 + lq * 4;
#pragma unroll
      for (int i = 0; i < 4; ++i)
        xp[(size_t)(rbase + i) * NC + col] = f2h(acc[mfi][nf][i] + bv);
    }
  }
}

// ---------------- phase 2: M-split MFMA recurrence ----------------
// bid: half = bid&1, dir = (bid>>1)&1, bl = bid>>2. Peer = bid^1.
// EX[slot][bid][out]: ull = {lo32: h fp32 bits, hi32: version}. Step t consumes
// version t from slot t&1; posts version t+1 to slot (t+1)&1.

__global__ __launch_bounds__(512, 2) void k_lstm(const uint4* __restrict__ WF,
                                                 const ushort* __restrict__ xp,
                                                 float* __restrict__ out,
                                                 ull* __restrict__ EX,
                                                 int b_base) {
  const int bid  = blockIdx.x;
  const int half = bid & 1;
  const int dir  = (bid >> 1) & 1;
  const int bl   = bid >> 2;
  const int tid  = threadIdx.x;
  const int w    = tid >> 6;
  const int lane = tid & 63;
  const int lq   = lane >> 4;
  const int n    = lane & 15;          // output within wave (4x lane-redundant)

  __shared__ ushort hp[2][256];        // full h (both halves), double-buffered
  __shared__ float  gbuf[8][4][16];    // gate bounce

  // ---- persistent weights: 32 frags, all registers, consumption order ----
  const uint4* wfb = WF + (size_t)(((dir * 2 + half) * 8 + w) * 32) * 64 + lane;
  uint4 wA[32];
#pragma unroll
  for (int f = 0; f < 32; ++f) wA[f] = wfb[(size_t)f * 64];

  if (tid < 256) { hp[0][tid] = 0; hp[1][tid] = 0; }
  float creg = 0.f;
  __syncthreads();

  const int dstep = dir ? -1 : 1;
  const int t0 = dir ? (Tn - 1) : 0;
  const ptrdiff_t xstr = (ptrdiff_t)dstep * NC;
  const ptrdiff_t ostr = (ptrdiff_t)dstep * 512;
  const ushort* px = xp + (size_t)(bl * Tn + t0) * NC + dir * 1024 + half * 128 + w * 16 + n;
  float* pout = out + (size_t)((b_base + bl) * Tn + t0) * 512 + dir * 256 + half * 128 + w * 16 + n;

  ull* exw = EX + (size_t)bid * 128 + w * 16 + n;            // + slot*NBmax*128
  const ull* exr = EX + (size_t)(bid ^ 1) * 128 + tid;       // pollers (tid<128)
  const int rbase = (half ^ 1) * 128;                        // remote half in hp

  int cur = 0;

#pragma unroll 1
  for (int t = 0; t < Tn; ++t) {
    // xp for this lane's 4 gates (consumed in tail; latency hidden)
    ushort xg0 = px[0], xg1 = px[256], xg2 = px[512], xg3 = px[768];
    px += xstr;

    f32x4 acc0 = {0.f,0.f,0.f,0.f}, acc1 = {0.f,0.f,0.f,0.f};
    f32x4 acc2 = {0.f,0.f,0.f,0.f}, acc3 = {0.f,0.f,0.f,0.f};

    // ---- phase 1: local kts (p=0..3); poll overlaps ----
    const char* hb = (const char*)hp[cur];
    const int kb0 = (4 * half) * 64;   // local kt byte base (wraps within 512)
#pragma unroll
    for (int p = 0; p < 4; ++p) {
      uint4 b = *(const uint4*)(hb + ((kb0 + p * 64) & 511) + lq * 16);
      acc0 = mf(wA[p * 4 + 0], b, acc0);
      acc1 = mf(wA[p * 4 + 1], b, acc1);
      acc2 = mf(wA[p * 4 + 2], b, acc2);
      acc3 = mf(wA[p * 4 + 3], b, acc3);
    }

    if (tid < 128) {                   // poll peer's h_{t-1} (posted ~1 step ago)
      const ull* pe = exr + (size_t)(t & 1) * NBmax * 128;
      ull v;
      do {
        v = __hip_atomic_load(pe, __ATOMIC_RELAXED, __HIP_MEMORY_SCOPE_AGENT);
      } while ((uint)(v >> 32) != (uint)t);
      hp[cur][rbase + tid] = f2h(__builtin_bit_cast(float, (uint)v));
    }
    barrier_lgkm();                    // remote half of h_{t-1} now in hp[cur]

    // ---- phase 2: remote kts (p=4..7) ----
    const int kb1 = (4 * (half ^ 1)) * 64;
#pragma unroll
    for (int p = 0; p < 4; ++p) {
      uint4 b = *(const uint4*)(hb + ((kb1 + p * 64) & 511) + lq * 16);
      acc0 = mf(wA[16 + p * 4 + 0], b, acc0);
      acc1 = mf(wA[16 + p * 4 + 1], b, acc1);
      acc2 = mf(wA[16 + p * 4 + 2], b, acc2);
      acc3 = mf(wA[16 + p * 4 + 3], b, acc3);
    }

    // ---- tail: bounce D col0 rows, activate, post h ----
    if ((lane & 15) == 0) {
      *(f32x4*)&gbuf[w][0][lq * 4] = acc0;
      *(f32x4*)&gbuf[w][1][lq * 4] = acc1;
      *(f32x4*)&gbuf[w][2][lq * 4] = acc2;
      *(f32x4*)&gbuf[w][3][lq * 4] = acc3;
    }
    // in-wave LDS dependency (compiler inserts lgkmcnt)
    float gi = gbuf[w][0][n] + h2f(xg0);
    float gf = gbuf[w][1][n] + h2f(xg1);
    float gg = gbuf[w][2][n] + h2f(xg2);
    float go = gbuf[w][3][n] + h2f(xg3);
    float iv = sig_(gi), fv = sig_(gf), gv = tanh_(gg), ov = sig_(go);
    creg = fv * creg + iv * gv;
    float h = ov * tanh_(creg);
    if (lane < 16) {
      *pout = h;
      ull pk = (ull)__builtin_bit_cast(uint, h) | ((ull)(uint)(t + 1) << 32);
      __hip_atomic_store(exw + (size_t)((t + 1) & 1) * NBmax * 128, pk,
                         __ATOMIC_RELAXED, __HIP_MEMORY_SCOPE_AGENT);
      hp[cur ^ 1][half * 128 + w * 16 + n] = f2h(h);
    }
    pout += ostr;
    barrier_lgkm();                    // local half of h_t visible to all waves
    cur ^= 1;
  }
}

// ---------------- host ----------------

extern "C" void kernel_launch(void* const* d_in, const int* in_sizes, int n_in,
                              void* d_out, int out_size, void* d_ws, size_t ws_size,
                              hipStream_t stream) {
  const float* x     = (const float*)d_in[0];
  const float* Wih_f = (const float*)d_in[1];
  const float* Whh_f = (const float*)d_in[2];
  const float* bih_f = (const float*)d_in[3];
  const float* bhh_f = (const float*)d_in[4];
  const float* Wih_b = (const float*)d_in[5];
  const float* Whh_b = (const float*)d_in[6];
  const float* bib_b = (const float*)d_in[7];
  const float* bhh_b = (const float*)d_in[8];
  float* out = (float*)d_out;

  const size_t szW16  = (size_t)NC * KT * 2;            // 2 MiB
  const size_t szBias = (size_t)NC * 4;
  const size_t szWF   = (size_t)1024 * 64 * 16;         // 1 MiB frag buffer
  const size_t szEX   = (size_t)2 * NBmax * 128 * 8;    // 256 KiB exchange

  int c = 0;
  size_t szA16 = 0, szXp = 0;
  for (int cc = 1; cc <= 16; cc *= 2) {
    size_t a = (size_t)(Bn / cc) * Tn * KT * 2;
    size_t p = (size_t)(Bn / cc) * Tn * NC * 2;
    if (szW16 + szBias + szWF + szEX + a + p <= ws_size) { c = cc; szA16 = a; szXp = p; break; }
  }
  if (c == 0) {
    k_bad<<<(out_size + 255) / 256, 256, 0, stream>>>(out, out_size);
    return;
  }

  char* ws = (char*)d_ws;
  ushort* W16   = (ushort*)ws;
  float*  biasc = (float*)(ws + szW16);
  uint4*  WF    = (uint4*)(ws + szW16 + szBias);
  ull*    EX    = (ull*)(ws + szW16 + szBias + szWF);
  ushort* A16   = (ushort*)(ws + szW16 + szBias + szWF + szEX);
  ushort* xp    = (ushort*)(ws + szW16 + szBias + szWF + szEX + szA16);

  {
    long n4 = (long)NC * (KT / 4);
    k_prep_w<<<(int)((n4 + 255) / 256), 256, 0, stream>>>(Wih_f, Wih_b, bih_f, bhh_f,
                                                          bib_b, bhh_b, W16, biasc);
  }
  k_prep_whh<<<(1024 * 64) / 256, 256, 0, stream>>>(Whh_f, Whh_b, WF);

  const int sizeB = Bn / c;
  for (int cb = 0; cb < c; ++cb) {
    const int b_base = cb * sizeB;
    {
      long nquad = (long)sizeB * Tn * KT / 4;
      k_prep_a<<<(int)((nquad + 255) / 256), 256, 0, stream>>>(
          x + (size_t)b_base * Tn * Dn, A16, nquad);
    }
    k_gemm<<<dim3(sizeB * 8 * 16), dim3(256), 0, stream>>>(A16, W16, biasc, xp);
    hipMemsetAsync(EX, 0, szEX, stream);
    k_lstm<<<dim3(4 * sizeB), dim3(512), 0, stream>>>(WF, xp, out, EX, b_base);
  }
}

// Round 11
// 1430.647 us; speedup vs baseline: 3.3270x; 1.1606x over previous
//
#include <hip/hip_runtime.h>
#include <cstdint>
#include <cstddef>

// Bidirectional LSTM  B=32 T=1024 D=512 H=256 (torch gate order i,f,g,o), fp32 in/out.
//
// Phase 1: xp = x @ Wih^T + bias  (fp16 MFMA GEMM, xp fp16)
// Phase 2: MFMA recurrence, 2-way M-split. Physical bid = half*(2*sizeB) + p,
//   p = (bl<<1)|dir  ->  peer = bid ^ (2*sizeB): with 128 blocks peers differ by 64
//   (== 0 mod 8) -> same XCD under round-robin dispatch -> exchange resolves in the
//   shared per-XCD L2, not cross-chiplet MALL. (Heuristic: perf-only, not correctness.)
//   Block owns 512 gate rows = 128 outputs; 8 waves; all 32 A-frags/wave in REGISTERS.
//   Exchange: 8B atomic {h fp32, version}, parity double-buffered EX[2]; step t
//   consumes version t from slot t&1 (early-probed BEFORE phase-1 MFMAs, re-polled
//   after). Barriers lgkmcnt-only (out/EX stores never drained).

typedef unsigned int   uint;
typedef unsigned short ushort;
typedef unsigned long long ull;

constexpr int Tn = 1024;
constexpr int Bn = 32;
constexpr int Dn = 512;
constexpr int Hn = 256;
constexpr int NC = 2048;          // 2 dirs * 4H
constexpr int KT = 512;           // K of the input projection
constexpr int NBmax = 128;        // max recurrence blocks (EX stride)

typedef _Float16 half8  __attribute__((ext_vector_type(8)));
typedef float    f32x4  __attribute__((ext_vector_type(4)));

__device__ __forceinline__ ushort f2h(float f) {
  _Float16 h = (_Float16)f;               // RNE
  return __builtin_bit_cast(ushort, h);
}
__device__ __forceinline__ float h2f(ushort s) {
  return (float)__builtin_bit_cast(_Float16, s);
}
__device__ __forceinline__ uint packh(float a, float b) {
  return (uint)f2h(a) | ((uint)f2h(b) << 16);
}
__device__ __forceinline__ f32x4 mf(uint4 a, uint4 b, f32x4 c) {
  return __builtin_amdgcn_mfma_f32_16x16x32_f16(
      __builtin_bit_cast(half8, a), __builtin_bit_cast(half8, b), c, 0, 0, 0);
}

__device__ __forceinline__ float sig_(float x) {
  x = fminf(fmaxf(x, -30.f), 30.f);
  return 1.f / (1.f + __expf(-x));
}
__device__ __forceinline__ float tanh_(float x) {
  x = fminf(fmaxf(x, -15.f), 15.f);
  float e = __expf(2.f * x);
  return (e - 1.f) / (e + 1.f);
}

// lgkm-only block barrier (no vmcnt drain: out/EX stores stay in flight)
__device__ __forceinline__ void barrier_lgkm() {
  asm volatile("s_waitcnt lgkmcnt(0)" ::: "memory");
  __builtin_amdgcn_s_barrier();
}

// ---------------- prep kernels ----------------

__global__ void k_prep_a(const float* __restrict__ x, ushort* __restrict__ a16, long nquad) {
  long i4 = (long)blockIdx.x * blockDim.x + threadIdx.x;
  if (i4 >= nquad) return;
  const float4 v = ((const float4*)x)[i4];
  ushort4 o;
  o.x = f2h(v.x); o.y = f2h(v.y); o.z = f2h(v.z); o.w = f2h(v.w);
  ((ushort4*)a16)[i4] = o;
}

__global__ void k_prep_w(const float* __restrict__ wf, const float* __restrict__ wb,
                         const float* __restrict__ bf1, const float* __restrict__ bf2,
                         const float* __restrict__ bb1, const float* __restrict__ bb2,
                         ushort* __restrict__ w16, float* __restrict__ biasc) {
  long i4 = (long)blockIdx.x * blockDim.x + threadIdx.x;
  if (i4 >= (long)NC * (KT / 4)) return;
  int n = (int)(i4 >> 7);
  int k4 = (int)(i4 & 127);
  int dir = n >> 10, g = n & 1023;
  const float* w = dir ? wb : wf;
  const float4 v = ((const float4*)(w + (size_t)g * Dn))[k4];
  ushort4 o;
  o.x = f2h(v.x); o.y = f2h(v.y); o.z = f2h(v.z); o.w = f2h(v.w);
  ((ushort4*)w16)[i4] = o;
  if (k4 == 0) biasc[n] = dir ? (bb1[g] + bb2[g]) : (bf1[g] + bf2[g]);
}

// Whh -> A-frags in per-(dir,half,wave) consumption order.
// frag = ((dir*2+half)*8 + w)*32 + p*4 + g ; phase p=0..7 (local kts first):
// ktphys = (p + 4*half) & 7 ; row = g*256 + half*128 + w*16 + (lane&15);
// k = ktphys*32 + (lane>>4)*8.
__global__ void k_prep_whh(const float* __restrict__ whhF, const float* __restrict__ whhB,
                           uint4* __restrict__ WF) {
  int t = blockIdx.x * blockDim.x + threadIdx.x;   // 0 .. 1024*64-1
  if (t >= 1024 * 64) return;
  int lane = t & 63;
  int frag = t >> 6;
  int g    = frag & 3;
  int p    = (frag >> 2) & 7;
  int w    = (frag >> 5) & 7;
  int half = (frag >> 8) & 1;
  int dir  = (frag >> 9) & 1;
  int row = g * 256 + half * 128 + w * 16 + (lane & 15);
  int ktphys = (p + 4 * half) & 7;
  int kb = ktphys * 32 + (lane >> 4) * 8;
  const float* whh = dir ? whhB : whhF;
  const float4* s = (const float4*)(whh + (size_t)row * Hn + kb);
  float4 v0 = s[0], v1 = s[1];
  WF[t] = (uint4){ packh(v0.x, v0.y), packh(v0.z, v0.w),
                   packh(v1.x, v1.y), packh(v1.z, v1.w) };
}

__global__ void k_bad(float* __restrict__ out, int n) {
  int i = blockIdx.x * blockDim.x + threadIdx.x;
  if (i < n) out[i] = 54321.f;
}

// ---------------- phase 1: fp16 MFMA GEMM (unchanged) ----------------

__device__ __forceinline__ void gload_lds16(const void* g, void* l) {
  __builtin_amdgcn_global_load_lds((const __attribute__((address_space(1))) void*)g,
                                   (__attribute__((address_space(3))) void*)l, 16, 0, 0);
}

__global__ __launch_bounds__(256) void k_gemm(const ushort* __restrict__ A,
                                              const ushort* __restrict__ W,
                                              const float* __restrict__ biasc,
                                              ushort* __restrict__ xp) {
  __shared__ __align__(16) ushort As[128 * 32];
  __shared__ __align__(16) ushort Bs[128 * 32];
  const int bid = blockIdx.x;
  const int m0 = (bid >> 4) * 128;
  const int n0 = (bid & 15) * 128;
  const int tid = threadIdx.x;
  const int wid = tid >> 6, lane = tid & 63;
  const int wr = wid >> 1, wcq = wid & 1;
  const int l16 = lane & 15, lq = lane >> 4;

  f32x4 acc[4][4] = {};

  for (int kt = 0; kt < KT; kt += 32) {
    __syncthreads();
#pragma unroll
    for (int i = 0; i < 2; ++i) {
      int ch = wid * 2 + i;
      int p = ch * 64 + lane;
      int r = p >> 2, gp = p & 3;
      int gs = gp ^ ((r >> 1) & 3);
      gload_lds16(A + (size_t)(m0 + r) * KT + kt + gs * 8, (char*)As + ch * 1024);
      gload_lds16(W + (size_t)(n0 + r) * KT + kt + gs * 8, (char*)Bs + ch * 1024);
    }
    __syncthreads();

    half8 af[4], bfr[4];
#pragma unroll
    for (int mfi = 0; mfi < 4; ++mfi) {
      int row = wr * 64 + mfi * 16 + l16;
      int g = lq ^ ((row >> 1) & 3);
      af[mfi] = *(const half8*)((const char*)As + row * 64 + g * 16);
    }
#pragma unroll
    for (int nf = 0; nf < 4; ++nf) {
      int row = wcq * 64 + nf * 16 + l16;
      int g = lq ^ ((row >> 1) & 3);
      bfr[nf] = *(const half8*)((const char*)Bs + row * 64 + g * 16);
    }
#pragma unroll
    for (int mfi = 0; mfi < 4; ++mfi)
#pragma unroll
      for (int nf = 0; nf < 4; ++nf)
        acc[mfi][nf] = __builtin_amdgcn_mfma_f32_16x16x32_f16(af[mfi], bfr[nf], acc[mfi][nf], 0, 0, 0);
  }

#pragma unroll
  for (int nf = 0; nf < 4; ++nf) {
    int col = n0 + wcq * 64 + nf * 16 + l16;
    float bv = biasc[col];
#pragma unroll
    for (int mfi = 0; mfi < 4; ++mfi) {
      int rbase = m0 + wr * 64 + mfi * 16 + lq * 4;
#pragma unroll
      for (int i = 0; i < 4; ++i)
        xp[(size_t)(rbase + i) * NC + col] = f2h(acc[mfi][nf][i] + bv);
    }
  }
}

// ---------------- phase 2: M-split MFMA recurrence, same-XCD pairing ----------------
// bid = half*pairStride + p ; p = (bl<<1)|dir ; peer = bid ^ pairStride.
// EX[slot][bid][out]: ull = {lo32: h fp32 bits, hi32: version}. Step t consumes
// version t from slot t&1 (early-probed); posts version t+1 to slot (t+1)&1.

__global__ __launch_bounds__(512, 2) void k_lstm(const uint4* __restrict__ WF,
                                                 const ushort* __restrict__ xp,
                                                 float* __restrict__ out,
                                                 ull* __restrict__ EX,
                                                 int b_base, int pairStride) {
  const int bid  = blockIdx.x;
  const int half = (bid & pairStride) ? 1 : 0;
  const int p_   = bid & (pairStride - 1);
  const int dir  = p_ & 1;
  const int bl   = p_ >> 1;
  const int tid  = threadIdx.x;
  const int w    = tid >> 6;
  const int lane = tid & 63;
  const int lq   = lane >> 4;
  const int n    = lane & 15;          // output within wave (4x lane-redundant)

  __shared__ ushort hp[2][256];        // full h (both halves), double-buffered
  __shared__ float  gbuf[8][4][16];    // gate bounce

  // ---- persistent weights: 32 frags, all registers, consumption order ----
  const uint4* wfb = WF + (size_t)(((dir * 2 + half) * 8 + w) * 32) * 64 + lane;
  uint4 wA[32];
#pragma unroll
  for (int f = 0; f < 32; ++f) wA[f] = wfb[(size_t)f * 64];

  if (tid < 256) { hp[0][tid] = 0; hp[1][tid] = 0; }
  float creg = 0.f;
  __syncthreads();

  const int dstep = dir ? -1 : 1;
  const int t0 = dir ? (Tn - 1) : 0;
  const ptrdiff_t xstr = (ptrdiff_t)dstep * NC;
  const ptrdiff_t ostr = (ptrdiff_t)dstep * 512;
  const ushort* px = xp + (size_t)(bl * Tn + t0) * NC + dir * 1024 + half * 128 + w * 16 + n;
  float* pout = out + (size_t)((b_base + bl) * Tn + t0) * 512 + dir * 256 + half * 128 + w * 16 + n;

  ull* exw = EX + (size_t)bid * 128 + w * 16 + n;                    // + slot*NBmax*128
  const ull* exr = EX + (size_t)(bid ^ pairStride) * 128 + tid;      // pollers (tid<128)
  const int rbase = (half ^ 1) * 128;                                // remote half in hp

  int cur = 0;

#pragma unroll 1
  for (int t = 0; t < Tn; ++t) {
    // xp for this lane's 4 gates (consumed in tail; latency hidden)
    ushort xg0 = px[0], xg1 = px[256], xg2 = px[512], xg3 = px[768];
    px += xstr;

    // early probe: issue peer load BEFORE phase-1 MFMAs (usually already posted)
    const ull* pe = exr + (size_t)(t & 1) * NBmax * 128;
    ull v0l = 0;
    if (tid < 128)
      v0l = __hip_atomic_load(pe, __ATOMIC_RELAXED, __HIP_MEMORY_SCOPE_AGENT);

    f32x4 acc0 = {0.f,0.f,0.f,0.f}, acc1 = {0.f,0.f,0.f,0.f};
    f32x4 acc2 = {0.f,0.f,0.f,0.f}, acc3 = {0.f,0.f,0.f,0.f};

    // ---- phase 1: local kts (p=0..3); probe latency hides under these ----
    const char* hb = (const char*)hp[cur];
    const int kb0 = (4 * half) * 64;   // local kt byte base (wraps within 512)
#pragma unroll
    for (int p = 0; p < 4; ++p) {
      uint4 b = *(const uint4*)(hb + ((kb0 + p * 64) & 511) + lq * 16);
      acc0 = mf(wA[p * 4 + 0], b, acc0);
      acc1 = mf(wA[p * 4 + 1], b, acc1);
      acc2 = mf(wA[p * 4 + 2], b, acc2);
      acc3 = mf(wA[p * 4 + 3], b, acc3);
    }

    if (tid < 128) {                   // finish poll (spin only if probe was stale)
      ull v = v0l;
      while ((uint)(v >> 32) != (uint)t)
        v = __hip_atomic_load(pe, __ATOMIC_RELAXED, __HIP_MEMORY_SCOPE_AGENT);
      hp[cur][rbase + tid] = f2h(__builtin_bit_cast(float, (uint)v));
    }
    barrier_lgkm();                    // remote half of h_{t-1} now in hp[cur]

    // ---- phase 2: remote kts (p=4..7) ----
    const int kb1 = (4 * (half ^ 1)) * 64;
#pragma unroll
    for (int p = 0; p < 4; ++p) {
      uint4 b = *(const uint4*)(hb + ((kb1 + p * 64) & 511) + lq * 16);
      acc0 = mf(wA[16 + p * 4 + 0], b, acc0);
      acc1 = mf(wA[16 + p * 4 + 1], b, acc1);
      acc2 = mf(wA[16 + p * 4 + 2], b, acc2);
      acc3 = mf(wA[16 + p * 4 + 3], b, acc3);
    }

    // ---- tail: bounce D col0 rows, activate, post h (EX first) ----
    if ((lane & 15) == 0) {
      *(f32x4*)&gbuf[w][0][lq * 4] = acc0;
      *(f32x4*)&gbuf[w][1][lq * 4] = acc1;
      *(f32x4*)&gbuf[w][2][lq * 4] = acc2;
      *(f32x4*)&gbuf[w][3][lq * 4] = acc3;
    }
    // in-wave LDS dependency (compiler inserts lgkmcnt)
    float gi = gbuf[w][0][n] + h2f(xg0);
    float gf = gbuf[w][1][n] + h2f(xg1);
    float gg = gbuf[w][2][n] + h2f(xg2);
    float go = gbuf[w][3][n] + h2f(xg3);
    float iv = sig_(gi), fv = sig_(gf), gv = tanh_(gg), ov = sig_(go);
    creg = fv * creg + iv * gv;
    float h = ov * tanh_(creg);
    if (lane < 16) {
      ull pk = (ull)__builtin_bit_cast(uint, h) | ((ull)(uint)(t + 1) << 32);
      __hip_atomic_store(exw + (size_t)((t + 1) & 1) * NBmax * 128, pk,
                         __ATOMIC_RELAXED, __HIP_MEMORY_SCOPE_AGENT);
      *pout = h;
      hp[cur ^ 1][half * 128 + w * 16 + n] = f2h(h);
    }
    pout += ostr;
    barrier_lgkm();                    // local half of h_t visible to all waves
    cur ^= 1;
  }
}

// ---------------- host ----------------

extern "C" void kernel_launch(void* const* d_in, const int* in_sizes, int n_in,
                              void* d_out, int out_size, void* d_ws, size_t ws_size,
                              hipStream_t stream) {
  const float* x     = (const float*)d_in[0];
  const float* Wih_f = (const float*)d_in[1];
  const float* Whh_f = (const float*)d_in[2];
  const float* bih_f = (const float*)d_in[3];
  const float* bhh_f = (const float*)d_in[4];
  const float* Wih_b = (const float*)d_in[5];
  const float* Whh_b = (const float*)d_in[6];
  const float* bib_b = (const float*)d_in[7];
  const float* bhh_b = (const float*)d_in[8];
  float* out = (float*)d_out;

  const size_t szW16  = (size_t)NC * KT * 2;            // 2 MiB
  const size_t szBias = (size_t)NC * 4;
  const size_t szWF   = (size_t)1024 * 64 * 16;         // 1 MiB frag buffer
  const size_t szEX   = (size_t)2 * NBmax * 128 * 8;    // 256 KiB exchange

  int c = 0;
  size_t szA16 = 0, szXp = 0;
  for (int cc = 1; cc <= 16; cc *= 2) {
    size_t a = (size_t)(Bn / cc) * Tn * KT * 2;
    size_t p = (size_t)(Bn / cc) * Tn * NC * 2;
    if (szW16 + szBias + szWF + szEX + a + p <= ws_size) { c = cc; szA16 = a; szXp = p; break; }
  }
  if (c == 0) {
    k_bad<<<(out_size + 255) / 256, 256, 0, stream>>>(out, out_size);
    return;
  }

  char* ws = (char*)d_ws;
  ushort* W16   = (ushort*)ws;
  float*  biasc = (float*)(ws + szW16);
  uint4*  WF    = (uint4*)(ws + szW16 + szBias);
  ull*    EX    = (ull*)(ws + szW16 + szBias + szWF);
  ushort* A16   = (ushort*)(ws + szW16 + szBias + szWF + szEX);
  ushort* xp    = (ushort*)(ws + szW16 + szBias + szWF + szEX + szA16);

  {
    long n4 = (long)NC * (KT / 4);
    k_prep_w<<<(int)((n4 + 255) / 256), 256, 0, stream>>>(Wih_f, Wih_b, bih_f, bhh_f,
                                                          bib_b, bhh_b, W16, biasc);
  }
  k_prep_whh<<<(1024 * 64) / 256, 256, 0, stream>>>(Whh_f, Whh_b, WF);

  const int sizeB = Bn / c;
  const int pairStride = 2 * sizeB;    // peers bid and bid^pairStride share an XCD
  for (int cb = 0; cb < c; ++cb) {
    const int b_base = cb * sizeB;
    {
      long nquad = (long)sizeB * Tn * KT / 4;
      k_prep_a<<<(int)((nquad + 255) / 256), 256, 0, stream>>>(
          x + (size_t)b_base * Tn * Dn, A16, nquad);
    }
    k_gemm<<<dim3(sizeB * 8 * 16), dim3(256), 0, stream>>>(A16, W16, biasc, xp);
    hipMemsetAsync(EX, 0, szEX, stream);
    k_lstm<<<dim3(4 * sizeB), dim3(512), 0, stream>>>(WF, xp, out, EX, b_base, pairStride);
  }
}